// Round 13
// baseline (1668.412 us; speedup 1.0000x reference)
//
#include <hip/hip_runtime.h>
#include <math.h>

#define F 1024
#define BM 128
#define BN 128
#define BK 8

typedef _Float16 h2 __attribute__((ext_vector_type(2)));
typedef _Float16 h4 __attribute__((ext_vector_type(4)));
typedef _Float16 h8 __attribute__((ext_vector_type(8)));
typedef float v4f __attribute__((ext_vector_type(4)));

static __device__ __forceinline__ float fmax3(float a, float b, float c) {
  float d;
  asm("v_max3_f32 %0, %1, %2, %3" : "=v"(d) : "v"(a), "v"(b), "v"(c));
  return d;
}
static __device__ __forceinline__ h2 pk_max(h2 a, h2 b) {
  h2 d;
  asm("v_pk_max_f16 %0, %1, %2" : "=v"(d) : "v"(a), "v"(b));
  return d;
}

// ---------------- LayerNorm: one WAVE per row, f32 out (R10-proven) ----------------
__global__ __launch_bounds__(256) void ln_kernel(const float* __restrict__ x,
                                                 const float* __restrict__ gamma,
                                                 const float* __restrict__ beta,
                                                 float* __restrict__ xn) {
  const int lane = threadIdx.x & 63;
  const int wv = threadIdx.x >> 6;
  const int row = blockIdx.x * 4 + wv;
  const float4* xr = (const float4*)(x + (size_t)row * F);
  float4 v[4];
  float s = 0.f;
#pragma unroll
  for (int j = 0; j < 4; ++j) {
    v[j] = xr[lane + 64 * j];
    s += v[j].x + v[j].y + v[j].z + v[j].w;
  }
#pragma unroll
  for (int off = 32; off; off >>= 1) s += __shfl_xor(s, off, 64);
  const float mu = s * (1.0f / F);
  float sq = 0.f;
#pragma unroll
  for (int j = 0; j < 4; ++j) {
    v[j].x -= mu; v[j].y -= mu; v[j].z -= mu; v[j].w -= mu;
    sq += v[j].x * v[j].x + v[j].y * v[j].y + v[j].z * v[j].z + v[j].w * v[j].w;
  }
#pragma unroll
  for (int off = 32; off; off >>= 1) sq += __shfl_xor(sq, off, 64);
  const float r = rsqrtf(sq * (1.0f / F) + 1e-5f);
  const float4* g4 = (const float4*)gamma;
  const float4* b4 = (const float4*)beta;
  float4* o = (float4*)(xn + (size_t)row * F);
#pragma unroll
  for (int j = 0; j < 4; ++j) {
    const int idx = lane + 64 * j;
    const float4 g = g4[idx];
    const float4 bb = b4[idx];
    float4 ov;
    ov.x = v[j].x * r * g.x + bb.x;
    ov.y = v[j].y * r * g.y + bb.y;
    ov.z = v[j].z * r * g.z + bb.z;
    ov.w = v[j].w * r * g.w + bb.w;
    o[idx] = ov;
  }
}

// ---------------- f32 tropical (max,+) GEMM, BK=8, 8 blocks/CU ----------------
// Inner loop identical to R10 (64 VGPR proven): v_add_f32 x2 + v_max3_f32 per k-pair
// per (m,n) = 3 cyc/update. BK=8 halves LDS (16.6 KB dbuf) -> 8 blocks/CU residency
// de-phases barrier-locked LDS/VALU bursts across independent blocks.
__global__ __launch_bounds__(256, 8) void trop_f(const float* __restrict__ A,
                                                 const float* __restrict__ Wm,
                                                 const float* __restrict__ bias,
                                                 _Float16* __restrict__ dsth,
                                                 float* __restrict__ outf,
                                                 int ntiles, int totrows, int fuse) {
  __shared__ float As[2][BK][BM + 4];  // transposed: As[buf][k][m]  8448 B
  __shared__ float Bs[2][BK][BN];      //                            8192 B

  const int tid = threadIdx.x;
  const int tx = tid & 15;
  const int ty = tid >> 4;
  const int row0 = blockIdx.y * BM;
  const int col0 = blockIdx.x * BN;
  const int kbase = blockIdx.z * ntiles * BK;

  const int ar = tid >> 1;         // A stage: row 0..127
  const int akq = (tid & 1) * 4;   // k offset 0 or 4
  const int bkr = tid >> 5;        // B stage: k-row 0..7
  const int bcg = (tid & 31) * 4;  // col offset

  const float* Asrc = A + (size_t)(row0 + ar) * F + kbase + akq;
  const float* Bsrc = Wm + (size_t)(kbase + bkr) * F + col0 + bcg;

  float acc[8][8];
#pragma unroll
  for (int m = 0; m < 8; ++m)
#pragma unroll
    for (int n = 0; n < 8; ++n) acc[m][n] = -INFINITY;

  // stage tile 0 into buf 0
  {
    const float4 a_st = *(const float4*)Asrc;
    const float4 b_st = *(const float4*)Bsrc;
    As[0][akq + 0][ar] = a_st.x;
    As[0][akq + 1][ar] = a_st.y;
    As[0][akq + 2][ar] = a_st.z;
    As[0][akq + 3][ar] = a_st.w;
    *(float4*)&Bs[0][bkr][bcg] = b_st;
  }
  __syncthreads();

  for (int kt = 0; kt < ntiles; ++kt) {
    const int cur = kt & 1;
    float4 a_st, b_st;
    if (kt + 1 < ntiles) {
      a_st = *(const float4*)(Asrc + (kt + 1) * BK);
      b_st = *(const float4*)(Bsrc + (size_t)(kt + 1) * BK * F);
    }

#pragma unroll
    for (int k = 0; k < BK; k += 2) {
      float a0[8], a1[8];
      *(float4*)&a0[0] = *(const float4*)&As[cur][k][ty * 8];
      *(float4*)&a0[4] = *(const float4*)&As[cur][k][ty * 8 + 4];
      *(float4*)&a1[0] = *(const float4*)&As[cur][k + 1][ty * 8];
      *(float4*)&a1[4] = *(const float4*)&As[cur][k + 1][ty * 8 + 4];
#pragma unroll
      for (int h = 0; h < 2; ++h) {  // column halves: cols h*64 + 4tx..+3
        float b0[4], b1[4];
        *(float4*)&b0[0] = *(const float4*)&Bs[cur][k][h * 64 + tx * 4];
        *(float4*)&b1[0] = *(const float4*)&Bs[cur][k + 1][h * 64 + tx * 4];
#pragma unroll
        for (int m = 0; m < 8; ++m)
#pragma unroll
          for (int n = 0; n < 4; ++n) {
            const float t0 = a0[m] + b0[n];  // v_add_f32 (2 cyc)
            const float t1 = a1[m] + b1[n];  // v_add_f32 (2 cyc)
            acc[m][h * 4 + n] = fmax3(acc[m][h * 4 + n], t0, t1);  // 2 cyc
          }
      }
    }

    if (kt + 1 < ntiles) {
      const int nxt = cur ^ 1;
      As[nxt][akq + 0][ar] = a_st.x;
      As[nxt][akq + 1][ar] = a_st.y;
      As[nxt][akq + 2][ar] = a_st.z;
      As[nxt][akq + 3][ar] = a_st.w;
      *(float4*)&Bs[nxt][bkr][bcg] = b_st;
      __syncthreads();
    }
  }

  if (fuse) {
    const float4 bv0 = *(const float4*)(bias + col0 + tx * 4);
    const float4 bv1 = *(const float4*)(bias + col0 + 64 + tx * 4);
#pragma unroll
    for (int m = 0; m < 8; ++m) {
      float* orow = outf + (size_t)(row0 + ty * 8 + m) * F + col0 + tx * 4;
      float4 o0, o1;
      o0.x = fmaxf(acc[m][0], bv0.x);
      o0.y = fmaxf(acc[m][1], bv0.y);
      o0.z = fmaxf(acc[m][2], bv0.z);
      o0.w = fmaxf(acc[m][3], bv0.w);
      o1.x = fmaxf(acc[m][4], bv1.x);
      o1.y = fmaxf(acc[m][5], bv1.y);
      o1.z = fmaxf(acc[m][6], bv1.z);
      o1.w = fmaxf(acc[m][7], bv1.w);
      *(float4*)orow = o0;
      *(float4*)(orow + 64) = o1;
    }
  } else {
    _Float16* base = dsth + (size_t)blockIdx.z * totrows * F;
#pragma unroll
    for (int m = 0; m < 8; ++m) {
      _Float16* orow = base + (size_t)(row0 + ty * 8 + m) * F + col0 + tx * 4;
      h4 o0 = {(_Float16)acc[m][0], (_Float16)acc[m][1],
               (_Float16)acc[m][2], (_Float16)acc[m][3]};
      h4 o1 = {(_Float16)acc[m][4], (_Float16)acc[m][5],
               (_Float16)acc[m][6], (_Float16)acc[m][7]};
      *(h4*)orow = o0;
      *(h4*)(orow + 64) = o1;
    }
  }
}

// ---------------- combine: out = max(NP fp16 partials, bias) in f32 ----------------
template <int NP>
__global__ __launch_bounds__(256) void combineNh(const _Float16* __restrict__ p,
                                                 size_t plane,
                                                 const float* __restrict__ bias,
                                                 float* __restrict__ out) {
  const int i = blockIdx.x * 256 + threadIdx.x;  // h8 index
  h8 v = ((const h8*)p)[i];
  h2* vv = (h2*)&v;
#pragma unroll
  for (int q = 1; q < NP; ++q) {
    const h8 u = ((const h8*)(p + (size_t)q * plane))[i];
    const h2* uu = (const h2*)&u;
#pragma unroll
    for (int j = 0; j < 4; ++j) vv[j] = pk_max(vv[j], uu[j]);
  }
  const int nb = (i & (F / 8 - 1)) * 8;
  const v4f bb0 = *(const v4f*)(bias + nb);
  const v4f bb1 = *(const v4f*)(bias + nb + 4);
  float4* o4 = (float4*)(out + (size_t)i * 8);
  float4 o0, o1;
  o0.x = fmaxf((float)v[0], bb0.x);
  o0.y = fmaxf((float)v[1], bb0.y);
  o0.z = fmaxf((float)v[2], bb0.z);
  o0.w = fmaxf((float)v[3], bb0.w);
  o1.x = fmaxf((float)v[4], bb1.x);
  o1.y = fmaxf((float)v[5], bb1.y);
  o1.z = fmaxf((float)v[6], bb1.z);
  o1.w = fmaxf((float)v[7], bb1.w);
  o4[0] = o0;
  o4[1] = o1;
}

extern "C" void kernel_launch(void* const* d_in, const int* in_sizes, int n_in,
                              void* d_out, int out_size, void* d_ws, size_t ws_size,
                              hipStream_t stream) {
  const float* x = (const float*)d_in[0];
  const float* Wm = (const float*)d_in[1];
  const float* bias = (const float*)d_in[2];
  const float* gamma = (const float*)d_in[3];
  const float* beta = (const float*)d_in[4];
  float* out = (float*)d_out;

  const int Brows = in_sizes[0] / F;  // 4096
  const size_t plane = (size_t)Brows * F;

  float* xn = (float*)d_ws;                   // plane f32 (16 MB)
  _Float16* parts = (_Float16*)(xn + plane);  // up to 8 planes fp16 (64 MB)

  ln_kernel<<<Brows / 4, 256, 0, stream>>>(x, gamma, beta, xn);

  const size_t need8 = plane * sizeof(float) + 8 * plane * sizeof(_Float16);
  const size_t need4 = plane * sizeof(float) + 4 * plane * sizeof(_Float16);
  const size_t need1 = plane * sizeof(float);
  if (ws_size >= need8) {
    dim3 grid(F / BN, Brows / BM, 8);  // 2048 blocks = 8 resident blocks/CU
    trop_f<<<grid, 256, 0, stream>>>(xn, Wm, bias, parts, nullptr,
                                     (F / BK) / 8, Brows, 0);
    combineNh<8><<<(int)(plane / 2048), 256, 0, stream>>>(parts, plane, bias, out);
  } else if (ws_size >= need4) {
    dim3 grid(F / BN, Brows / BM, 4);
    trop_f<<<grid, 256, 0, stream>>>(xn, Wm, bias, parts, nullptr,
                                     (F / BK) / 4, Brows, 0);
    combineNh<4><<<(int)(plane / 2048), 256, 0, stream>>>(parts, plane, bias, out);
  } else if (ws_size >= need1) {
    dim3 grid(F / BN, Brows / BM, 1);
    trop_f<<<grid, 256, 0, stream>>>(xn, Wm, bias, nullptr, out, F / BK, Brows, 1);
  }
}

// Round 14
// 309.701 us; speedup vs baseline: 5.3872x; 5.3872x over previous
//
#include <hip/hip_runtime.h>
#include <math.h>

#define F 1024

static __device__ __forceinline__ float fmax3(float a, float b, float c) {
  float d;
  asm("v_max3_f32 %0, %1, %2, %3" : "=v"(d) : "v"(a), "v"(b), "v"(c));
  return d;
}

// ---------------- LayerNorm: one WAVE per row, f32 out (R10-proven) ----------------
__global__ __launch_bounds__(256) void ln_kernel(const float* __restrict__ x,
                                                 const float* __restrict__ gamma,
                                                 const float* __restrict__ beta,
                                                 float* __restrict__ xn) {
  const int lane = threadIdx.x & 63;
  const int wv = threadIdx.x >> 6;
  const int row = blockIdx.x * 4 + wv;
  const float4* xr = (const float4*)(x + (size_t)row * F);
  float4 v[4];
  float s = 0.f;
#pragma unroll
  for (int j = 0; j < 4; ++j) {
    v[j] = xr[lane + 64 * j];
    s += v[j].x + v[j].y + v[j].z + v[j].w;
  }
#pragma unroll
  for (int off = 32; off; off >>= 1) s += __shfl_xor(s, off, 64);
  const float mu = s * (1.0f / F);
  float sq = 0.f;
#pragma unroll
  for (int j = 0; j < 4; ++j) {
    v[j].x -= mu; v[j].y -= mu; v[j].z -= mu; v[j].w -= mu;
    sq += v[j].x * v[j].x + v[j].y * v[j].y + v[j].z * v[j].z + v[j].w * v[j].w;
  }
#pragma unroll
  for (int off = 32; off; off >>= 1) sq += __shfl_xor(sq, off, 64);
  const float r = rsqrtf(sq * (1.0f / F) + 1e-5f);
  const float4* g4 = (const float4*)gamma;
  const float4* b4 = (const float4*)beta;
  float4* o = (float4*)(xn + (size_t)row * F);
#pragma unroll
  for (int j = 0; j < 4; ++j) {
    const int idx = lane + 64 * j;
    const float4 g = g4[idx];
    const float4 bb = b4[idx];
    float4 ov;
    ov.x = v[j].x * r * g.x + bb.x;
    ov.y = v[j].y * r * g.y + bb.y;
    ov.z = v[j].z * r * g.z + bb.z;
    ov.w = v[j].w * r * g.w + bb.w;
    o[idx] = ov;
  }
}

// -------- tropical (max,+) GEMM, LDS-free, SGPR-broadcast A --------
// Wave w of block (bx,by): rows by*32 + w*8 .. +7 (wave-uniform), col = bx*64 + lane.
// A[row][k] is wave-uniform -> scalar loads (s_load) + free broadcast into
// v_add_f32 (1 SGPR operand allowed). B[k][col] -> coalesced dword loads, L2-hot.
// Per 8-k chunk per lane: 8 vmem + 8 smem + 96 VALU (1.5 instr/update ISA floor).
// No LDS, no barriers, no split-K: out = max(acc, bias) written directly in f32.
__global__ __launch_bounds__(256) void trop_s(const float* __restrict__ A,
                                              const float* __restrict__ Wm,
                                              const float* __restrict__ bias,
                                              float* __restrict__ out) {
  const int lane = threadIdx.x & 63;
  // force wave-uniformity so the compiler scalarizes all A addressing
  const int wv = __builtin_amdgcn_readfirstlane((int)(threadIdx.x >> 6));
  const int col = blockIdx.x * 64 + lane;
  const int row0 = blockIdx.y * 32 + wv * 8;

  const float* arow0 = A + (size_t)row0 * F;  // uniform base
  const float* wcol = Wm + col;

  float acc[8];
#pragma unroll
  for (int r = 0; r < 8; ++r) acc[r] = -INFINITY;

  for (int kc = 0; kc < F; kc += 8) {
    // B: 8 strided dword loads (coalesced across lanes), reused by 8 rows
    float b[8];
#pragma unroll
    for (int j = 0; j < 8; ++j) b[j] = wcol[(size_t)(kc + j) * F];
    // A: 8 rows x 8 k, wave-uniform -> s_load_dwordx8 each
#pragma unroll
    for (int r = 0; r < 8; ++r) {
      const float* ar = arow0 + (size_t)r * F + kc;
      float a[8];
#pragma unroll
      for (int j = 0; j < 8; ++j) a[j] = ar[j];
#pragma unroll
      for (int j = 0; j < 8; j += 2) {
        const float t0 = a[j] + b[j];          // v_add_f32 (sgpr + vgpr)
        const float t1 = a[j + 1] + b[j + 1];  // v_add_f32
        acc[r] = fmax3(acc[r], t0, t1);        // v_max3_f32
      }
    }
  }

  const float bv = bias[col];
#pragma unroll
  for (int r = 0; r < 8; ++r)
    out[(size_t)(row0 + r) * F + col] = fmaxf(acc[r], bv);
}

extern "C" void kernel_launch(void* const* d_in, const int* in_sizes, int n_in,
                              void* d_out, int out_size, void* d_ws, size_t ws_size,
                              hipStream_t stream) {
  const float* x = (const float*)d_in[0];
  const float* Wm = (const float*)d_in[1];
  const float* bias = (const float*)d_in[2];
  const float* gamma = (const float*)d_in[3];
  const float* beta = (const float*)d_in[4];
  float* out = (float*)d_out;

  const int Brows = in_sizes[0] / F;  // 4096
  float* xn = (float*)d_ws;           // [B, F] f32 = 16 MB

  ln_kernel<<<Brows / 4, 256, 0, stream>>>(x, gamma, beta, xn);

  dim3 grid(F / 64, Brows / 32);  // 16 x 128 = 2048 blocks = 8 blocks/CU
  trop_s<<<grid, 256, 0, stream>>>(xn, Wm, bias, out);
}

// Round 15
// 216.327 us; speedup vs baseline: 7.7124x; 1.4316x over previous
//
#include <hip/hip_runtime.h>
#include <math.h>

#define F 1024
#define BM 128
#define BN 128
#define BK 8

typedef _Float16 h2 __attribute__((ext_vector_type(2)));
typedef _Float16 h4 __attribute__((ext_vector_type(4)));
typedef _Float16 h8 __attribute__((ext_vector_type(8)));
typedef float v4f __attribute__((ext_vector_type(4)));

static __device__ __forceinline__ float fmax3(float a, float b, float c) {
  float d;
  asm("v_max3_f32 %0, %1, %2, %3" : "=v"(d) : "v"(a), "v"(b), "v"(c));
  return d;
}
static __device__ __forceinline__ h2 pk_max(h2 a, h2 b) {
  h2 d;
  asm("v_pk_max_f16 %0, %1, %2" : "=v"(d) : "v"(a), "v"(b));
  return d;
}

// ---------------- LayerNorm: one WAVE per row, f32 out (R10-proven) ----------------
__global__ __launch_bounds__(256) void ln_kernel(const float* __restrict__ x,
                                                 const float* __restrict__ gamma,
                                                 const float* __restrict__ beta,
                                                 float* __restrict__ xn) {
  const int lane = threadIdx.x & 63;
  const int wv = threadIdx.x >> 6;
  const int row = blockIdx.x * 4 + wv;
  const float4* xr = (const float4*)(x + (size_t)row * F);
  float4 v[4];
  float s = 0.f;
#pragma unroll
  for (int j = 0; j < 4; ++j) {
    v[j] = xr[lane + 64 * j];
    s += v[j].x + v[j].y + v[j].z + v[j].w;
  }
#pragma unroll
  for (int off = 32; off; off >>= 1) s += __shfl_xor(s, off, 64);
  const float mu = s * (1.0f / F);
  float sq = 0.f;
#pragma unroll
  for (int j = 0; j < 4; ++j) {
    v[j].x -= mu; v[j].y -= mu; v[j].z -= mu; v[j].w -= mu;
    sq += v[j].x * v[j].x + v[j].y * v[j].y + v[j].z * v[j].z + v[j].w * v[j].w;
  }
#pragma unroll
  for (int off = 32; off; off >>= 1) sq += __shfl_xor(sq, off, 64);
  const float r = rsqrtf(sq * (1.0f / F) + 1e-5f);
  const float4* g4 = (const float4*)gamma;
  const float4* b4 = (const float4*)beta;
  float4* o = (float4*)(xn + (size_t)row * F);
#pragma unroll
  for (int j = 0; j < 4; ++j) {
    const int idx = lane + 64 * j;
    const float4 g = g4[idx];
    const float4 bb = b4[idx];
    float4 ov;
    ov.x = v[j].x * r * g.x + bb.x;
    ov.y = v[j].y * r * g.y + bb.y;
    ov.z = v[j].z * r * g.z + bb.z;
    ov.w = v[j].w * r * g.w + bb.w;
    o[idx] = ov;
  }
}

// ---------------- f32 tropical (max,+) GEMM, BK=8, no VGPR cap ----------------
// R10's proven inner loop (v_add_f32 x2 + v_max3_f32 per k-pair per (m,n), 3 cyc/update).
// BK=8 halves LDS to 16.6 KB dbuf; with natural ~64 VGPR this admits 8 blocks/CU,
// de-phasing the barrier-locked LDS/VALU bursts across independent blocks.
// NOTE: no second __launch_bounds__ arg — R13's (256,8) clamped VGPR to 64 and the
// allocator spilled (VGPR_Count=32, 8.4 GB scratch traffic, 1584 us).
__global__ __launch_bounds__(256) void trop_f(const float* __restrict__ A,
                                              const float* __restrict__ Wm,
                                              const float* __restrict__ bias,
                                              _Float16* __restrict__ dsth,
                                              float* __restrict__ outf,
                                              int ntiles, int totrows, int fuse) {
  __shared__ float As[2][BK][BM + 4];  // transposed: As[buf][k][m]  8448 B
  __shared__ float Bs[2][BK][BN];      //                            8192 B

  const int tid = threadIdx.x;
  const int tx = tid & 15;
  const int ty = tid >> 4;
  const int row0 = blockIdx.y * BM;
  const int col0 = blockIdx.x * BN;
  const int kbase = blockIdx.z * ntiles * BK;

  const int ar = tid >> 1;         // A stage: row 0..127
  const int akq = (tid & 1) * 4;   // k offset 0 or 4
  const int bkr = tid >> 5;        // B stage: k-row 0..7
  const int bcg = (tid & 31) * 4;  // col offset

  const float* Asrc = A + (size_t)(row0 + ar) * F + kbase + akq;
  const float* Bsrc = Wm + (size_t)(kbase + bkr) * F + col0 + bcg;

  float acc[8][8];
#pragma unroll
  for (int m = 0; m < 8; ++m)
#pragma unroll
    for (int n = 0; n < 8; ++n) acc[m][n] = -INFINITY;

  // stage tile 0 into buf 0
  {
    const float4 a_st = *(const float4*)Asrc;
    const float4 b_st = *(const float4*)Bsrc;
    As[0][akq + 0][ar] = a_st.x;
    As[0][akq + 1][ar] = a_st.y;
    As[0][akq + 2][ar] = a_st.z;
    As[0][akq + 3][ar] = a_st.w;
    *(float4*)&Bs[0][bkr][bcg] = b_st;
  }
  __syncthreads();

  for (int kt = 0; kt < ntiles; ++kt) {
    const int cur = kt & 1;
    float4 a_st, b_st;
    if (kt + 1 < ntiles) {
      a_st = *(const float4*)(Asrc + (kt + 1) * BK);
      b_st = *(const float4*)(Bsrc + (size_t)(kt + 1) * BK * F);
    }

#pragma unroll
    for (int k = 0; k < BK; k += 2) {
      float a0[8], a1[8];
      *(float4*)&a0[0] = *(const float4*)&As[cur][k][ty * 8];
      *(float4*)&a0[4] = *(const float4*)&As[cur][k][ty * 8 + 4];
      *(float4*)&a1[0] = *(const float4*)&As[cur][k + 1][ty * 8];
      *(float4*)&a1[4] = *(const float4*)&As[cur][k + 1][ty * 8 + 4];
#pragma unroll
      for (int h = 0; h < 2; ++h) {  // column halves: cols h*64 + 4tx..+3
        float b0[4], b1[4];
        *(float4*)&b0[0] = *(const float4*)&Bs[cur][k][h * 64 + tx * 4];
        *(float4*)&b1[0] = *(const float4*)&Bs[cur][k + 1][h * 64 + tx * 4];
#pragma unroll
        for (int m = 0; m < 8; ++m)
#pragma unroll
          for (int n = 0; n < 4; ++n) {
            const float t0 = a0[m] + b0[n];  // v_add_f32 (2 cyc)
            const float t1 = a1[m] + b1[n];  // v_add_f32 (2 cyc)
            acc[m][h * 4 + n] = fmax3(acc[m][h * 4 + n], t0, t1);  // 2 cyc
          }
      }
    }

    if (kt + 1 < ntiles) {
      const int nxt = cur ^ 1;
      As[nxt][akq + 0][ar] = a_st.x;
      As[nxt][akq + 1][ar] = a_st.y;
      As[nxt][akq + 2][ar] = a_st.z;
      As[nxt][akq + 3][ar] = a_st.w;
      *(float4*)&Bs[nxt][bkr][bcg] = b_st;
      __syncthreads();
    }
  }

  if (fuse) {
    const float4 bv0 = *(const float4*)(bias + col0 + tx * 4);
    const float4 bv1 = *(const float4*)(bias + col0 + 64 + tx * 4);
#pragma unroll
    for (int m = 0; m < 8; ++m) {
      float* orow = outf + (size_t)(row0 + ty * 8 + m) * F + col0 + tx * 4;
      float4 o0, o1;
      o0.x = fmaxf(acc[m][0], bv0.x);
      o0.y = fmaxf(acc[m][1], bv0.y);
      o0.z = fmaxf(acc[m][2], bv0.z);
      o0.w = fmaxf(acc[m][3], bv0.w);
      o1.x = fmaxf(acc[m][4], bv1.x);
      o1.y = fmaxf(acc[m][5], bv1.y);
      o1.z = fmaxf(acc[m][6], bv1.z);
      o1.w = fmaxf(acc[m][7], bv1.w);
      *(float4*)orow = o0;
      *(float4*)(orow + 64) = o1;
    }
  } else {
    _Float16* base = dsth + (size_t)blockIdx.z * totrows * F;
#pragma unroll
    for (int m = 0; m < 8; ++m) {
      _Float16* orow = base + (size_t)(row0 + ty * 8 + m) * F + col0 + tx * 4;
      h4 o0 = {(_Float16)acc[m][0], (_Float16)acc[m][1],
               (_Float16)acc[m][2], (_Float16)acc[m][3]};
      h4 o1 = {(_Float16)acc[m][4], (_Float16)acc[m][5],
               (_Float16)acc[m][6], (_Float16)acc[m][7]};
      *(h4*)orow = o0;
      *(h4*)(orow + 64) = o1;
    }
  }
}

// ---------------- combine: out = max(NP fp16 partials, bias) in f32 ----------------
template <int NP>
__global__ __launch_bounds__(256) void combineNh(const _Float16* __restrict__ p,
                                                 size_t plane,
                                                 const float* __restrict__ bias,
                                                 float* __restrict__ out) {
  const int i = blockIdx.x * 256 + threadIdx.x;  // h8 index
  h8 v = ((const h8*)p)[i];
  h2* vv = (h2*)&v;
#pragma unroll
  for (int q = 1; q < NP; ++q) {
    const h8 u = ((const h8*)(p + (size_t)q * plane))[i];
    const h2* uu = (const h2*)&u;
#pragma unroll
    for (int j = 0; j < 4; ++j) vv[j] = pk_max(vv[j], uu[j]);
  }
  const int nb = (i & (F / 8 - 1)) * 8;
  const v4f bb0 = *(const v4f*)(bias + nb);
  const v4f bb1 = *(const v4f*)(bias + nb + 4);
  float4* o4 = (float4*)(out + (size_t)i * 8);
  float4 o0, o1;
  o0.x = fmaxf((float)v[0], bb0.x);
  o0.y = fmaxf((float)v[1], bb0.y);
  o0.z = fmaxf((float)v[2], bb0.z);
  o0.w = fmaxf((float)v[3], bb0.w);
  o1.x = fmaxf((float)v[4], bb1.x);
  o1.y = fmaxf((float)v[5], bb1.y);
  o1.z = fmaxf((float)v[6], bb1.z);
  o1.w = fmaxf((float)v[7], bb1.w);
  o4[0] = o0;
  o4[1] = o1;
}

extern "C" void kernel_launch(void* const* d_in, const int* in_sizes, int n_in,
                              void* d_out, int out_size, void* d_ws, size_t ws_size,
                              hipStream_t stream) {
  const float* x = (const float*)d_in[0];
  const float* Wm = (const float*)d_in[1];
  const float* bias = (const float*)d_in[2];
  const float* gamma = (const float*)d_in[3];
  const float* beta = (const float*)d_in[4];
  float* out = (float*)d_out;

  const int Brows = in_sizes[0] / F;  // 4096
  const size_t plane = (size_t)Brows * F;

  float* xn = (float*)d_ws;                   // plane f32 (16 MB)
  _Float16* parts = (_Float16*)(xn + plane);  // up to 8 planes fp16 (64 MB)

  ln_kernel<<<Brows / 4, 256, 0, stream>>>(x, gamma, beta, xn);

  const size_t need8 = plane * sizeof(float) + 8 * plane * sizeof(_Float16);
  const size_t need4 = plane * sizeof(float) + 4 * plane * sizeof(_Float16);
  const size_t need1 = plane * sizeof(float);
  if (ws_size >= need8) {
    dim3 grid(F / BN, Brows / BM, 8);  // 2048 blocks = 8 resident blocks/CU
    trop_f<<<grid, 256, 0, stream>>>(xn, Wm, bias, parts, nullptr,
                                     (F / BK) / 8, Brows, 0);
    combineNh<8><<<(int)(plane / 2048), 256, 0, stream>>>(parts, plane, bias, out);
  } else if (ws_size >= need4) {
    dim3 grid(F / BN, Brows / BM, 4);
    trop_f<<<grid, 256, 0, stream>>>(xn, Wm, bias, parts, nullptr,
                                     (F / BK) / 4, Brows, 0);
    combineNh<4><<<(int)(plane / 2048), 256, 0, stream>>>(parts, plane, bias, out);
  } else if (ws_size >= need1) {
    dim3 grid(F / BN, Brows / BM, 1);
    trop_f<<<grid, 256, 0, stream>>>(xn, Wm, bias, nullptr, out, F / BK, Brows, 1);
  }
}